// Round 1
// baseline (584.189 us; speedup 1.0000x reference)
//
#include <hip/hip_runtime.h>
#include <math.h>

#define B_ 4
#define T_ 2048
#define C_ 1024
#define H_ 16
#define D_ 64
#define M_ (B_*T_)      // 8192
#define N1_ (3*C_)      // 3072

typedef __attribute__((ext_vector_type(8))) short bf16x8;
typedef __attribute__((ext_vector_type(4))) short bf16x4;
typedef __attribute__((ext_vector_type(4))) float f32x4;

__device__ __forceinline__ short f2bf(float f){
  union { float f; unsigned u; } v; v.f = f;
  unsigned r = (v.u + 0x7fffu + ((v.u >> 16) & 1u)) >> 16;
  return (short)r;
}

__device__ __forceinline__ void gll16(const void* g, void* l){
  __builtin_amdgcn_global_load_lds((const __attribute__((address_space(1))) void*)g,
                                   (__attribute__((address_space(3))) void*)l, 16, 0, 0);
}

// ---- convert x (f32) -> bf16 ----
__global__ __launch_bounds__(256) void convx(const float* __restrict__ x, short* __restrict__ xb, int n){
  int i = (blockIdx.x*256 + threadIdx.x)*8;
  if (i >= n) return;
  float4 a = *(const float4*)(x+i), b = *(const float4*)(x+i+4);
  bf16x8 o;
  o[0]=f2bf(a.x); o[1]=f2bf(a.y); o[2]=f2bf(a.z); o[3]=f2bf(a.w);
  o[4]=f2bf(b.x); o[5]=f2bf(b.y); o[6]=f2bf(b.z); o[7]=f2bf(b.w);
  *(bf16x8*)(xb+i) = o;
}

// ---- transpose W (K,N) f32 -> Wt (N,K) bf16 ----
__global__ __launch_bounds__(256) void transw(const float* __restrict__ W, short* __restrict__ Wt, int K, int N){
  __shared__ float tl[64][72];   // pad: 72 floats/row = 288B, 16B-aligned rows
  int tid = threadIdx.x;
  int n0 = blockIdx.x*64, k0 = blockIdx.y*64;
  #pragma unroll
  for (int i=0;i<4;i++){
    int row = (tid>>4) + i*16;
    int col4 = (tid&15)*4;
    float4 v = *(const float4*)&W[(size_t)(k0+row)*N + n0 + col4];
    *(float4*)&tl[row][col4] = v;
  }
  __syncthreads();
  #pragma unroll
  for (int i=0;i<2;i++){
    int nr = (tid>>3) + i*32;
    int ch = tid&7;
    bf16x8 o;
    #pragma unroll
    for (int e=0;e<8;e++) o[e] = f2bf(tl[ch*8+e][nr]);
    *(bf16x8*)&Wt[(size_t)(n0+nr)*K + k0 + ch*8] = o;
  }
}

// ---- GEMM: out(M,N) = A(M,K) @ Bt(N,K)^T + bias.  128x128 tile, 4 waves ----
template<int OUTBF>
__global__ __launch_bounds__(256) void gemm_bt(const short* __restrict__ A, const short* __restrict__ Bt,
           const float* __restrict__ bias, short* __restrict__ outb, float* __restrict__ outf,
           int M, int N, int K)
{
  __shared__ short As[128*32];
  __shared__ short Bs[128*32];
  const int tid = threadIdx.x;
  const int wv = tid >> 6, ln = tid & 63;
  const int lnr = ln & 15, lg = ln >> 4;
  const int m0 = blockIdx.y * 128, n0 = blockIdx.x * 128;
  const int wm = wv >> 1, wn = wv & 1;
  f32x4 acc[4][4];
  #pragma unroll
  for(int i=0;i<4;i++)
    #pragma unroll
    for(int j=0;j<4;j++) acc[i][j] = (f32x4){0.f,0.f,0.f,0.f};

  for (int k0 = 0; k0 < K; k0 += 32){
    #pragma unroll
    for (int c = 0; c < 2; c++){
      int i = c*256 + tid;
      gll16(A  + (size_t)(m0 + (i>>2))*K + k0 + (i&3)*8, (void*)(As + (c*256 + wv*64)*8));
      gll16(Bt + (size_t)(n0 + (i>>2))*K + k0 + (i&3)*8, (void*)(Bs + (c*256 + wv*64)*8));
    }
    __syncthreads();   // drains vmcnt -> LDS ready
    bf16x8 af[4], bfr[4];
    #pragma unroll
    for (int mi=0;mi<4;mi++) af[mi]  = *(const bf16x8*)&As[(wm*64 + mi*16 + lnr)*32 + lg*8];
    #pragma unroll
    for (int ni=0;ni<4;ni++) bfr[ni] = *(const bf16x8*)&Bs[(wn*64 + ni*16 + lnr)*32 + lg*8];
    #pragma unroll
    for (int mi=0;mi<4;mi++)
      #pragma unroll
      for (int ni=0;ni<4;ni++)
        acc[mi][ni] = __builtin_amdgcn_mfma_f32_16x16x32_bf16(af[mi], bfr[ni], acc[mi][ni], 0,0,0);
    __syncthreads();   // all reads done before next stage overwrites
  }

  #pragma unroll
  for (int mi=0;mi<4;mi++){
    #pragma unroll
    for (int ni=0;ni<4;ni++){
      int col = n0 + wn*64 + ni*16 + lnr;
      float bv = bias[col];
      #pragma unroll
      for (int r=0;r<4;r++){
        int row = m0 + wm*64 + mi*16 + lg*4 + r;
        float v = acc[mi][ni][r] + bv;
        if (OUTBF) outb[(size_t)row*N + col] = f2bf(v);
        else       outf[(size_t)row*N + col] = v;
      }
    }
  }
}

// ---- transpose V slice of qkv -> vt (B*H, D, T) bf16 ----
__global__ __launch_bounds__(256) void transv(const short* __restrict__ qkv, short* __restrict__ vt){
  __shared__ short tl[64][72];
  int tid = threadIdx.x;
  int t0 = blockIdx.x*64, bh = blockIdx.y;
  int b = bh>>4, h = bh&15;
  int tr = tid>>2, cc = (tid&3)*16;
  const short* src = &qkv[(size_t)(b*T_ + t0 + tr)*N1_ + 2*C_ + h*D_ + cc];
  #pragma unroll
  for (int i=0;i<4;i++){
    bf16x4 v = *(const bf16x4*)(src + i*4);
    *(bf16x4*)&tl[tr][cc + i*4] = v;
  }
  __syncthreads();
  int d = tid>>2, tc = (tid&3)*16;
  #pragma unroll
  for (int i=0;i<2;i++){
    bf16x8 o;
    #pragma unroll
    for (int e=0;e<8;e++) o[e] = tl[tc + i*8 + e][d];
    *(bf16x8*)&vt[(size_t)(bh*D_ + d)*T_ + t0 + tc + i*8] = o;
  }
}

// ---- flash attention: 4 waves/block, wave owns 16 q-rows; K/V direct from L2 ----
__global__ __launch_bounds__(256) void attn(const short* __restrict__ qkv, const short* __restrict__ vt,
           const int* __restrict__ mask, short* __restrict__ yb)
{
  __shared__ short pl[4][16*80];   // per-wave P transpose buffer, stride 80 (160B, 16B-aligned)
  const int tid = threadIdx.x;
  const int wv = tid>>6, ln = tid&63;
  const int lnr = ln&15, lg = ln>>4;
  const int qblk = blockIdx.x;     // 0..31
  const int bh = blockIdx.y;       // 0..63
  const int b = bh >> 4, h = bh & 15;
  const int q0 = qblk*64 + wv*16;

  bf16x8 aq[2];
  #pragma unroll
  for (int kk=0;kk<2;kk++)
    aq[kk] = *(const bf16x8*)&qkv[(size_t)(b*T_ + q0 + lnr)*N1_ + h*D_ + kk*32 + lg*8];

  f32x4 o[4];
  float mrow[4], lsum[4];
  #pragma unroll
  for (int ct=0;ct<4;ct++) o[ct] = (f32x4){0.f,0.f,0.f,0.f};
  #pragma unroll
  for (int r=0;r<4;r++){ mrow[r] = -INFINITY; lsum[r] = 0.f; }

  for (int jt = 0; jt <= qblk; jt++){
    int j0 = jt*64;
    f32x4 s[4];
    #pragma unroll
    for (int ct=0; ct<4; ct++){
      const short* kbase = &qkv[(size_t)(b*T_ + j0 + ct*16 + lnr)*N1_ + C_ + h*D_ + lg*8];
      bf16x8 bk0 = *(const bf16x8*)kbase;
      bf16x8 bk1 = *(const bf16x8*)(kbase + 32);
      f32x4 z = (f32x4){0.f,0.f,0.f,0.f};
      z = __builtin_amdgcn_mfma_f32_16x16x32_bf16(aq[0], bk0, z, 0,0,0);
      z = __builtin_amdgcn_mfma_f32_16x16x32_bf16(aq[1], bk1, z, 0,0,0);
      s[ct] = z;
    }
    // scale + causal/pad mask + row max
    float pm[4] = {-INFINITY,-INFINITY,-INFINITY,-INFINITY};
    #pragma unroll
    for (int ct=0;ct<4;ct++){
      int kcol = j0 + ct*16 + lnr;
      int am = mask[b*T_ + kcol];
      #pragma unroll
      for (int r=0;r<4;r++){
        int qrow = q0 + lg*4 + r;
        float v = s[ct][r]*0.125f;
        v = (kcol <= qrow && am != 0) ? v : -INFINITY;
        s[ct][r] = v;
        pm[r] = fmaxf(pm[r], v);
      }
    }
    #pragma unroll
    for (int r=0;r<4;r++){
      #pragma unroll
      for (int msk=1; msk<16; msk<<=1)
        pm[r] = fmaxf(pm[r], __shfl_xor(pm[r], msk));
    }
    float alpha[4];
    #pragma unroll
    for (int r=0;r<4;r++){
      float nm = fmaxf(mrow[r], pm[r]);
      alpha[r] = __expf(mrow[r] - nm);   // -inf -> 0 on first tile
      mrow[r] = nm;
    }
    // p = exp(s-m); stash bf16 P into per-wave LDS (D-layout -> row-major)
    #pragma unroll
    for (int ct=0;ct<4;ct++){
      #pragma unroll
      for (int r=0;r<4;r++){
        float sv = s[ct][r];
        float p = (sv == -INFINITY) ? 0.f : __expf(sv - mrow[r]);
        s[ct][r] = p;
        pl[wv][(lg*4+r)*80 + ct*16 + lnr] = f2bf(p);
      }
    }
    float ps[4];
    #pragma unroll
    for (int r=0;r<4;r++){
      ps[r] = s[0][r] + s[1][r] + s[2][r] + s[3][r];
      #pragma unroll
      for (int msk=1; msk<16; msk<<=1)
        ps[r] += __shfl_xor(ps[r], msk);
      lsum[r] = lsum[r]*alpha[r] + ps[r];
    }
    #pragma unroll
    for (int ct=0;ct<4;ct++)
      #pragma unroll
      for (int r=0;r<4;r++) o[ct][r] *= alpha[r];
    // read P back as A-fragments (wave-local; compiler orders LDS deps)
    bf16x8 pa[2];
    #pragma unroll
    for (int kk=0;kk<2;kk++)
      pa[kk] = *(const bf16x8*)&pl[wv][lnr*80 + kk*32 + lg*8];
    // PV
    #pragma unroll
    for (int ct=0;ct<4;ct++){
      const short* vb = &vt[(size_t)(bh*D_ + ct*16 + lnr)*T_ + j0 + lg*8];
      o[ct] = __builtin_amdgcn_mfma_f32_16x16x32_bf16(pa[0], *(const bf16x8*)vb,      o[ct], 0,0,0);
      o[ct] = __builtin_amdgcn_mfma_f32_16x16x32_bf16(pa[1], *(const bf16x8*)(vb+32), o[ct], 0,0,0);
    }
  }
  #pragma unroll
  for (int r=0;r<4;r++) lsum[r] = 1.f / lsum[r];
  #pragma unroll
  for (int ct=0;ct<4;ct++)
    #pragma unroll
    for (int r=0;r<4;r++)
      yb[(size_t)(b*T_ + q0 + lg*4 + r)*C_ + h*D_ + ct*16 + lnr] = f2bf(o[ct][r]*lsum[r]);
}

extern "C" void kernel_launch(void* const* d_in, const int* in_sizes, int n_in,
                              void* d_out, int out_size, void* d_ws, size_t ws_size,
                              hipStream_t stream){
  const float* x     = (const float*)d_in[0];
  const int*   mask  = (const int*)d_in[1];
  const float* Wqkv  = (const float*)d_in[2];
  const float* bqkv  = (const float*)d_in[3];
  const float* Wproj = (const float*)d_in[4];
  const float* bproj = (const float*)d_in[5];
  float* out = (float*)d_out;

  char* w = (char*)d_ws;
  short* xb     = (short*)w; w += (size_t)M_*C_*2;      // 16 MB
  short* wqkvT  = (short*)w; w += (size_t)N1_*C_*2;     // 6 MB
  short* wprojT = (short*)w; w += (size_t)C_*C_*2;      // 2 MB
  short* qkvb   = (short*)w; w += (size_t)M_*N1_*2;     // 48 MB
  short* vtb    = (short*)w; w += (size_t)B_*H_*D_*T_*2;// 16 MB
  short* yb     = (short*)w; w += (size_t)M_*C_*2;      // 16 MB

  convx<<<dim3((M_*C_)/(256*8)), 256, 0, stream>>>(x, xb, M_*C_);
  transw<<<dim3(N1_/64, C_/64), 256, 0, stream>>>(Wqkv, wqkvT, C_, N1_);
  transw<<<dim3(C_/64,  C_/64), 256, 0, stream>>>(Wproj, wprojT, C_, C_);
  gemm_bt<1><<<dim3(N1_/128, M_/128), 256, 0, stream>>>(xb, wqkvT, bqkv, qkvb, nullptr, M_, N1_, C_);
  transv<<<dim3(T_/64, B_*H_), 256, 0, stream>>>(qkvb, vtb);
  attn<<<dim3(T_/64, B_*H_), 256, 0, stream>>>(qkvb, vtb, mask, yb);
  gemm_bt<0><<<dim3(C_/128, M_/128), 256, 0, stream>>>(yb, wprojT, bproj, nullptr, out, M_, C_, C_);
}

// Round 2
// 303.762 us; speedup vs baseline: 1.9232x; 1.9232x over previous
//
#include <hip/hip_runtime.h>
#include <math.h>

#define B_ 4
#define T_ 2048
#define C_ 1024
#define H_ 16
#define D_ 64
#define M_ (B_*T_)      // 8192
#define N1_ (3*C_)      // 3072
#define NCH_ 16         // q-chunks of 128 rows per (b,h)

typedef __attribute__((ext_vector_type(8))) short bf16x8;
typedef __attribute__((ext_vector_type(4))) short bf16x4;
typedef __attribute__((ext_vector_type(4))) float f32x4;
typedef __attribute__((ext_vector_type(16))) float f32x16;

__device__ __forceinline__ short f2bf(float f){
  union { float f; unsigned u; } v; v.f = f;
  unsigned r = (v.u + 0x7fffu + ((v.u >> 16) & 1u)) >> 16;
  return (short)r;
}

__device__ __forceinline__ unsigned cvtpk(float lo, float hi){
  unsigned r;
  asm("v_cvt_pk_bf16_f32 %0, %1, %2" : "=v"(r) : "v"(lo), "v"(hi));
  return r;
}

__device__ __forceinline__ void gll16(const void* g, void* l){
  __builtin_amdgcn_global_load_lds((const __attribute__((address_space(1))) void*)g,
                                   (__attribute__((address_space(3))) void*)l, 16, 0, 0);
}

// ---- convert x (f32) -> bf16 ----
__global__ __launch_bounds__(256) void convx(const float* __restrict__ x, short* __restrict__ xb, int n){
  int i = (blockIdx.x*256 + threadIdx.x)*8;
  if (i >= n) return;
  float4 a = *(const float4*)(x+i), b = *(const float4*)(x+i+4);
  bf16x8 o;
  o[0]=f2bf(a.x); o[1]=f2bf(a.y); o[2]=f2bf(a.z); o[3]=f2bf(a.w);
  o[4]=f2bf(b.x); o[5]=f2bf(b.y); o[6]=f2bf(b.z); o[7]=f2bf(b.w);
  *(bf16x8*)(xb+i) = o;
}

// ---- transpose W (K,N) f32 -> Wt (N,K) bf16 ----
__global__ __launch_bounds__(256) void transw(const float* __restrict__ W, short* __restrict__ Wt, int K, int N){
  __shared__ float tl[64][72];
  int tid = threadIdx.x;
  int n0 = blockIdx.x*64, k0 = blockIdx.y*64;
  #pragma unroll
  for (int i=0;i<4;i++){
    int row = (tid>>4) + i*16;
    int col4 = (tid&15)*4;
    float4 v = *(const float4*)&W[(size_t)(k0+row)*N + n0 + col4];
    *(float4*)&tl[row][col4] = v;
  }
  __syncthreads();
  #pragma unroll
  for (int i=0;i<2;i++){
    int nr = (tid>>3) + i*32;
    int ch = tid&7;
    bf16x8 o;
    #pragma unroll
    for (int e=0;e<8;e++) o[e] = f2bf(tl[ch*8+e][nr]);
    *(bf16x8*)&Wt[(size_t)(n0+nr)*K + k0 + ch*8] = o;
  }
}

// ---- GEMM: out(M,N) = A(M,K) @ Bt(N,K)^T + bias.  128x128 tile, 4 waves ----
template<int OUTBF>
__global__ __launch_bounds__(256) void gemm_bt(const short* __restrict__ A, const short* __restrict__ Bt,
           const float* __restrict__ bias, short* __restrict__ outb, float* __restrict__ outf,
           int M, int N, int K)
{
  __shared__ short As[128*32];
  __shared__ short Bs[128*32];
  const int tid = threadIdx.x;
  const int wv = tid >> 6, ln = tid & 63;
  const int lnr = ln & 15, lg = ln >> 4;
  const int m0 = blockIdx.y * 128, n0 = blockIdx.x * 128;
  const int wm = wv >> 1, wn = wv & 1;
  f32x4 acc[4][4];
  #pragma unroll
  for(int i=0;i<4;i++)
    #pragma unroll
    for(int j=0;j<4;j++) acc[i][j] = (f32x4){0.f,0.f,0.f,0.f};

  for (int k0 = 0; k0 < K; k0 += 32){
    #pragma unroll
    for (int c = 0; c < 2; c++){
      int i = c*256 + tid;
      gll16(A  + (size_t)(m0 + (i>>2))*K + k0 + (i&3)*8, (void*)(As + (c*256 + wv*64)*8));
      gll16(Bt + (size_t)(n0 + (i>>2))*K + k0 + (i&3)*8, (void*)(Bs + (c*256 + wv*64)*8));
    }
    __syncthreads();
    bf16x8 af[4], bfr[4];
    #pragma unroll
    for (int mi=0;mi<4;mi++) af[mi]  = *(const bf16x8*)&As[(wm*64 + mi*16 + lnr)*32 + lg*8];
    #pragma unroll
    for (int ni=0;ni<4;ni++) bfr[ni] = *(const bf16x8*)&Bs[(wn*64 + ni*16 + lnr)*32 + lg*8];
    #pragma unroll
    for (int mi=0;mi<4;mi++)
      #pragma unroll
      for (int ni=0;ni<4;ni++)
        acc[mi][ni] = __builtin_amdgcn_mfma_f32_16x16x32_bf16(af[mi], bfr[ni], acc[mi][ni], 0,0,0);
    __syncthreads();
  }

  #pragma unroll
  for (int mi=0;mi<4;mi++){
    #pragma unroll
    for (int ni=0;ni<4;ni++){
      int col = n0 + wn*64 + ni*16 + lnr;
      float bv = bias[col];
      #pragma unroll
      for (int r=0;r<4;r++){
        int row = m0 + wm*64 + mi*16 + lg*4 + r;
        float v = acc[mi][ni][r] + bv;
        if (OUTBF) outb[(size_t)row*N + col] = f2bf(v);
        else       outf[(size_t)row*N + col] = v;
      }
    }
  }
}

// ---- transpose V slice of qkv -> vt (B*H, D, T) bf16 ----
__global__ __launch_bounds__(256) void transv(const short* __restrict__ qkv, short* __restrict__ vt){
  __shared__ short tl[64][72];
  int tid = threadIdx.x;
  int t0 = blockIdx.x*64, bh = blockIdx.y;
  int b = bh>>4, h = bh&15;
  int tr = tid>>2, cc = (tid&3)*16;
  const short* src = &qkv[(size_t)(b*T_ + t0 + tr)*N1_ + 2*C_ + h*D_ + cc];
  #pragma unroll
  for (int i=0;i<4;i++){
    bf16x4 v = *(const bf16x4*)(src + i*4);
    *(bf16x4*)&tl[tr][cc + i*4] = v;
  }
  __syncthreads();
  int d = tid>>2, tc = (tid&3)*16;
  #pragma unroll
  for (int i=0;i<2;i++){
    bf16x8 o;
    #pragma unroll
    for (int e=0;e<8;e++) o[e] = tl[tc + i*8 + e][d];
    *(bf16x8*)&vt[(size_t)(bh*D_ + d)*T_ + t0 + tc + i*8] = o;
  }
}

// ---- flash attention v2: 32x32 swapped QK^T, zero LDS, in-register softmax ----
// 4 waves/block, wave owns 32 q-rows; block does chunk x and chunk 15-x (causal balance).
__global__ __launch_bounds__(256) void attn2(const short* __restrict__ qkv, const short* __restrict__ vt,
           const int* __restrict__ mask, short* __restrict__ yb)
{
  const int tid = threadIdx.x;
  const int wv = tid>>6, ln = tid&63;
  const int l31 = ln & 31, hi = ln >> 5;
  const int bh = blockIdx.y, b = bh>>4, h = bh&15;
  const float cexp = 0.18033688f;   // 0.125 * log2(e)

  #pragma unroll 1
  for (int half = 0; half < 2; half++){
    const int chunk = (half == 0) ? (int)blockIdx.x : (NCH_-1 - (int)blockIdx.x);
    const int q0w = chunk*128 + wv*32;

    // Q fragments (B-operand): lane holds Q[q0w + l31][ds*16 + hi*8 + e]
    bf16x8 qf[4];
    const short* qbase = qkv + (size_t)(b*T_ + q0w + l31)*N1_ + h*D_ + hi*8;
    #pragma unroll
    for (int ds=0; ds<4; ds++) qf[ds] = *(const bf16x8*)(qbase + ds*16);

    f32x16 o0, o1;
    #pragma unroll
    for (int r=0;r<16;r++){ o0[r]=0.f; o1[r]=0.f; }
    float mrow = -INFINITY, lsum = 0.f;

    const int ntiles = ((q0w + 31) >> 6) + 1;
    for (int jt = 0; jt < ntiles; jt++){
      const int j0 = jt << 6;
      int mval = mask[b*T_ + j0 + ln];
      unsigned long long bm = __ballot(mval != 0);

      // K fragments (A-operand) + QK^T: s[kt] = S^T[kt*32 + krow][q]
      const short* kbase = qkv + (size_t)(b*T_ + j0 + l31)*N1_ + C_ + h*D_ + hi*8;
      f32x16 s0, s1;
      #pragma unroll
      for (int r=0;r<16;r++){ s0[r]=0.f; s1[r]=0.f; }
      #pragma unroll
      for (int ds=0; ds<4; ds++){
        bf16x8 k0 = *(const bf16x8*)(kbase + ds*16);
        bf16x8 k1 = *(const bf16x8*)(kbase + (size_t)32*N1_ + ds*16);
        s0 = __builtin_amdgcn_mfma_f32_32x32x16_bf16(k0, qf[ds], s0, 0,0,0);
        s1 = __builtin_amdgcn_mfma_f32_32x32x16_bf16(k1, qf[ds], s1, 0,0,0);
      }

      // masking: raw-s domain (-inf)
      const int qglob = q0w + l31;
      const bool allm = (bm == ~0ull);
      if (!allm){
        #pragma unroll
        for (int r=0;r<16;r++){
          int kr = (r&3) + 8*(r>>2) + 4*hi;
          bool ok0 = (j0 + kr      <= qglob) && ((bm >> kr) & 1);
          bool ok1 = (j0 + kr + 32 <= qglob) && ((bm >> (kr+32)) & 1);
          s0[r] = ok0 ? s0[r] : -INFINITY;
          s1[r] = ok1 ? s1[r] : -INFINITY;
        }
      } else if (j0 + 63 > q0w){   // diagonal tile: causal only
        #pragma unroll
        for (int r=0;r<16;r++){
          int kr = (r&3) + 8*(r>>2) + 4*hi;
          s0[r] = (j0 + kr      <= qglob) ? s0[r] : -INFINITY;
          s1[r] = (j0 + kr + 32 <= qglob) ? s1[r] : -INFINITY;
        }
      }

      // tile max (in-register tree + one cross-half swap)
      float t[8];
      #pragma unroll
      for (int i=0;i<8;i++) t[i] = fmaxf(fmaxf(s0[i], s0[i+8]), fmaxf(s1[i], s1[i+8]));
      #pragma unroll
      for (int i=0;i<4;i++) t[i] = fmaxf(t[i], t[i+4]);
      float pm = fmaxf(fmaxf(t[0],t[1]), fmaxf(t[2],t[3]));
      pm = fmaxf(pm, __shfl_xor(pm, 32));

      // defer-max: rescale only when max grew past threshold (always on first tile)
      if (!__all(pm - mrow <= 40.0f)){
        float nm = fmaxf(mrow, pm);
        float alpha = __builtin_amdgcn_exp2f((mrow - nm)*cexp);
        lsum *= alpha;
        mrow = nm;
        #pragma unroll
        for (int r=0;r<16;r++){
          int qsrc = (r&3) + 8*(r>>2) + 4*hi;
          float aO = __shfl(alpha, qsrc);
          o0[r] *= aO; o1[r] *= aO;
        }
      }

      // p = exp2((s - m)*c)
      f32x16 p0, p1;
      #pragma unroll
      for (int r=0;r<16;r++){
        p0[r] = __builtin_amdgcn_exp2f((s0[r]-mrow)*cexp);
        p1[r] = __builtin_amdgcn_exp2f((s1[r]-mrow)*cexp);
      }
      // tile sum
      float u[8];
      #pragma unroll
      for (int i=0;i<8;i++) u[i] = (p0[i]+p0[i+8]) + (p1[i]+p1[i+8]);
      #pragma unroll
      for (int i=0;i<4;i++) u[i] = u[i] + u[i+4];
      float ps = (u[0]+u[1]) + (u[2]+u[3]);
      ps += __shfl_xor(ps, 32);
      lsum += ps;

      // V fragments (hoisted so VMEM latency hides under pack ops)
      const short* vbase = vt + (size_t)(bh*D_ + l31)*T_ + j0 + hi*8;
      bf16x8 vf0[4], vf1[4];
      #pragma unroll
      for (int kt2=0; kt2<4; kt2++){
        vf0[kt2] = *(const bf16x8*)(vbase + kt2*16);
        vf1[kt2] = *(const bf16x8*)(vbase + (size_t)32*T_ + kt2*16);
      }

      // pack P -> bf16 A-fragments: cvt_pk + cross-half swap (no LDS)
      unsigned LA[2][4], LB[2][4], SA[2][4], SB[2][4];
      #pragma unroll
      for (int rq=0; rq<4; rq++){
        LA[0][rq] = cvtpk(p0[4*rq],   p0[4*rq+1]);
        LB[0][rq] = cvtpk(p0[4*rq+2], p0[4*rq+3]);
        LA[1][rq] = cvtpk(p1[4*rq],   p1[4*rq+1]);
        LB[1][rq] = cvtpk(p1[4*rq+2], p1[4*rq+3]);
      }
      #pragma unroll
      for (int kt=0; kt<2; kt++)
        #pragma unroll
        for (int rq=0; rq<4; rq++){
          SA[kt][rq] = (unsigned)__shfl_xor((int)LA[kt][rq], 32);
          SB[kt][rq] = (unsigned)__shfl_xor((int)LB[kt][rq], 32);
        }

      // PV: o[dt] += P(32q x 64k) . V(64k x 32d)
      #pragma unroll
      for (int kt2=0; kt2<4; kt2++){
        const int kt = kt2>>1, sub = kt2&1;
        union { unsigned u[4]; bf16x8 v; } pf;
        pf.u[0] = hi ? SA[kt][2*sub+1] : LA[kt][2*sub];
        pf.u[1] = hi ? SB[kt][2*sub+1] : LB[kt][2*sub];
        pf.u[2] = hi ? LA[kt][2*sub+1] : SA[kt][2*sub];
        pf.u[3] = hi ? LB[kt][2*sub+1] : SB[kt][2*sub];
        o0 = __builtin_amdgcn_mfma_f32_32x32x16_bf16(pf.v, vf0[kt2], o0, 0,0,0);
        o1 = __builtin_amdgcn_mfma_f32_32x32x16_bf16(pf.v, vf1[kt2], o1, 0,0,0);
      }
    }

    // epilogue: normalize + store bf16
    float linv = 1.0f / lsum;
    #pragma unroll
    for (int r=0;r<16;r++){
      int qsrc = (r&3) + 8*(r>>2) + 4*hi;
      float lv = __shfl(linv, qsrc);
      size_t base = (size_t)(b*T_ + q0w + qsrc)*C_ + h*D_ + l31;
      yb[base]      = f2bf(o0[r]*lv);
      yb[base + 32] = f2bf(o1[r]*lv);
    }
  }
}

extern "C" void kernel_launch(void* const* d_in, const int* in_sizes, int n_in,
                              void* d_out, int out_size, void* d_ws, size_t ws_size,
                              hipStream_t stream){
  const float* x     = (const float*)d_in[0];
  const int*   mask  = (const int*)d_in[1];
  const float* Wqkv  = (const float*)d_in[2];
  const float* bqkv  = (const float*)d_in[3];
  const float* Wproj = (const float*)d_in[4];
  const float* bproj = (const float*)d_in[5];
  float* out = (float*)d_out;

  char* w = (char*)d_ws;
  short* xb     = (short*)w; w += (size_t)M_*C_*2;
  short* wqkvT  = (short*)w; w += (size_t)N1_*C_*2;
  short* wprojT = (short*)w; w += (size_t)C_*C_*2;
  short* qkvb   = (short*)w; w += (size_t)M_*N1_*2;
  short* vtb    = (short*)w; w += (size_t)B_*H_*D_*T_*2;
  short* yb     = (short*)w; w += (size_t)M_*C_*2;

  convx<<<dim3((M_*C_)/(256*8)), 256, 0, stream>>>(x, xb, M_*C_);
  transw<<<dim3(N1_/64, C_/64), 256, 0, stream>>>(Wqkv, wqkvT, C_, N1_);
  transw<<<dim3(C_/64,  C_/64), 256, 0, stream>>>(Wproj, wprojT, C_, C_);
  gemm_bt<1><<<dim3(N1_/128, M_/128), 256, 0, stream>>>(xb, wqkvT, bqkv, qkvb, nullptr, M_, N1_, C_);
  transv<<<dim3(T_/64, B_*H_), 256, 0, stream>>>(qkvb, vtb);
  attn2<<<dim3(NCH_/2, B_*H_), 256, 0, stream>>>(qkvb, vtb, mask, yb);
  gemm_bt<0><<<dim3(C_/128, M_/128), 256, 0, stream>>>(yb, wprojT, bproj, nullptr, out, M_, C_, C_);
}